// Round 10
// baseline (655.871 us; speedup 1.0000x reference)
//
#include <hip/hip_runtime.h>
#include <cstddef>

typedef unsigned short u16;
typedef float f32x4 __attribute__((ext_vector_type(4)));
typedef short bf16x8 __attribute__((ext_vector_type(8)));

// Problem dims
#define SDIM 256
#define CDIM 64
#define NDIM 2000
#define TDIM 500

#define MAT  (SDIM*SDIM)   // 65536
#define HMAT (CDIM*SDIM)   // 16384

#define GRID 256           // mega-kernel blocks: 1/CU, guaranteed co-resident

// ---- workspace layout (float offsets into d_ws) ---- all PROBABILITY domain
#define OFF_POW    0u                        // [25][256][256] f32: pow[i] = Tm^(i+1)
#define OFF_R2     (OFF_POW + 25u*MAT)       // Tm^50
#define OFF_R4     (OFF_R2 + MAT)            // Tm^100
#define OFF_R8     (OFF_R4 + MAT)            // Tm^200
#define OFF_R16    (OFF_R8 + MAT)            // Tm^400
#define OFF_HEADS  (OFF_R16 + MAT)           // [20][64][256] f32: H_b = h0 @ Tm^25b
#define OFF_CW     (OFF_HEADS + 20u*HMAT)    // [500][64] f32 chain-weight probs
#define OFF_EPROB  (OFF_CW + 32000u)         // [256][2000] f32 emission probs
#define OFF_ET     (OFF_EPROB + 512000u)     // u16: E^T bf16 [2048 n][256 k]
#define OFF_PT     (OFF_ET + 262144u)        // u16: P^T bf16 [25][256 n][256 k]
#define OFF_HDB    (OFF_PT + 819200u)        // u16: heads bf16 [20][64][256]
#define OFF_HB     (OFF_HDB + 163840u)       // u16: hidden bf16 [500][64][256]
#define OFF_CNT    (OFF_HB + 4096000u)       // unsigned barrier counter (memset to 0 per call)
// end ~ 31 MB

// d_out layout: log_obs [500][2000] | log_obs_ [500][64][2000] | log_hidden [500][64][256]
#define OUT_OBSB  1000000u
#define OUT_HIDB  65000000u

#define TP 260   // padded LDS tile stride (floats)

__device__ __forceinline__ float waveMax(float v) {
#pragma unroll
  for (int o = 32; o >= 1; o >>= 1) v = fmaxf(v, __shfl_xor(v, o));
  return v;
}
__device__ __forceinline__ float waveSum(float v) {
#pragma unroll
  for (int o = 32; o >= 1; o >>= 1) v += __shfl_xor(v, o);
  return v;
}
__device__ __forceinline__ u16 f2b(float f) {
  union { float f; unsigned u; } x; x.f = f;
  return (u16)((x.u + 0x7fffu + ((x.u >> 16) & 1u)) >> 16);
}

// device-scope monotonic grid barrier (all GRID blocks co-resident: 1 block/CU)
__device__ __forceinline__ void grid_sync(unsigned* cnt, unsigned target) {
  __syncthreads();
  if (threadIdx.x == 0) {
    __threadfence();                                   // release: my writes visible device-wide
    atomicAdd(cnt, 1u);
    while (atomicOr(cnt, 0u) < target) __builtin_amdgcn_s_sleep(8);
    __threadfence();                                   // acquire: see others' writes
  }
  __syncthreads();
}

// ---------------- prep: one row's softmax -> probabilities (register-cached) ----------------
__device__ __forceinline__ void prep_row(int b,
    const float* __restrict__ si, const float* __restrict__ cw,
    const float* __restrict__ em, const float* __restrict__ tm,
    const float* __restrict__ mask, float* __restrict__ ws,
    float* rA, float* rB) {
  const float* src; const float* msk = nullptr; float* dst; int len;
  if (b < 64)       { src = si + b*SDIM;                 dst = ws + OFF_HEADS + b*SDIM; len = SDIM; }
  else if (b < 564) { int r = b - 64;  src = cw + r*64;  dst = ws + OFF_CW + r*64;      len = 64;   }
  else if (b < 820) { int r = b - 564; src = tm + (size_t)r*SDIM; dst = ws + OFF_POW + (size_t)r*SDIM; len = SDIM; }
  else              { int r = b - 820; src = em + (size_t)r*NDIM; dst = ws + OFF_EPROB + (size_t)r*NDIM; len = NDIM; msk = mask + (size_t)r*NDIM; }
  int tid = threadIdx.x;
  __syncthreads();   // guard shared rA/rB reuse across row iterations
  float v[8];
  float m = -INFINITY;
#pragma unroll
  for (int i = 0; i < 8; ++i) {
    int idx = tid + i*256;
    if (idx < len) {
      float x = src[idx];
      if (msk) x += __logf(msk[idx]);
      v[i] = x;
      m = fmaxf(m, x);
    } else v[i] = -INFINITY;
  }
  m = waveMax(m);
  if ((tid & 63) == 0) rA[tid >> 6] = m;
  __syncthreads();
  m = fmaxf(fmaxf(rA[0], rA[1]), fmaxf(rA[2], rA[3]));
  float s = 0.f;
#pragma unroll
  for (int i = 0; i < 8; ++i) s += __expf(v[i] - m);
  s = waveSum(s);
  if ((tid & 63) == 0) rB[tid >> 6] = s;
  __syncthreads();
  s = rB[0] + rB[1] + rB[2] + rB[3];
  float inv = 1.f / s;
#pragma unroll
  for (int i = 0; i < 8; ++i) {
    int idx = tid + i*256;
    if (idx < len) dst[idx] = __expf(v[i] - m) * inv;
  }
}

// ---------------- plain fp32 prob-domain GEMM tile (chain) ----------------
__device__ void gemm_tile(const float* __restrict__ A, const float* __restrict__ B,
                          float* __restrict__ C, int r0, int n0,
                          float (*As)[68], float (*Bs)[68]) {
  int tid = threadIdx.x;
  float acc[4][4] = {};
  int tm4 = (tid >> 4) << 2, tn4 = (tid & 15) << 2;
  for (int kc = 0; kc < 4; ++kc) {
    __syncthreads();
    {
      int rr = tid >> 2, p = tid & 3;
      const float* sA = A + (size_t)(r0 + rr)*SDIM + kc*64 + p*16;
#pragma unroll
      for (int i = 0; i < 16; ++i) As[p*16 + i][rr] = sA[i];
    }
    {
      int kk = tid >> 2, p = tid & 3;
      const float* sB = B + (size_t)(kc*64 + kk)*SDIM + n0 + p*16;
#pragma unroll
      for (int i = 0; i < 16; ++i) Bs[kk][p*16 + i] = sB[i];
    }
    __syncthreads();
#pragma unroll 8
    for (int k = 0; k < 64; ++k) {
      float4 av = *(const float4*)&As[k][tm4];
      float4 bv = *(const float4*)&Bs[k][tn4];
      float a[4] = {av.x, av.y, av.z, av.w};
      float bb[4] = {bv.x, bv.y, bv.z, bv.w};
#pragma unroll
      for (int i = 0; i < 4; ++i)
#pragma unroll
        for (int j = 0; j < 4; ++j) acc[i][j] += a[i]*bb[j];
    }
  }
  __syncthreads();
#pragma unroll
  for (int i = 0; i < 4; ++i)
    *(float4*)&C[(size_t)(r0 + tm4 + i)*SDIM + n0 + tn4] =
        make_float4(acc[i][0], acc[i][1], acc[i][2], acc[i][3]);
}

// ---------------- one 64x64 transpose tile fp32 -> bf16 [n][256] ----------------
__device__ void trans_tile(const float* __restrict__ src, int ldn, int nReal,
                           u16* __restrict__ dst, int n0, int k0,
                           float (*tile)[65]) {
  int tid = threadIdx.x;
  __syncthreads();   // guard reuse
  {
    int kk = tid >> 2, p = tid & 3;
    const float* s = src + (size_t)(k0 + kk)*ldn + n0 + p*16;
#pragma unroll
    for (int i = 0; i < 16; ++i) {
      int n = n0 + p*16 + i;
      tile[p*16 + i][kk] = (n < nReal) ? s[i] : 0.f;
    }
  }
  __syncthreads();
  {
    int rr = tid >> 2, kq = (tid & 3) * 16;
    unsigned w[8];
#pragma unroll
    for (int i = 0; i < 8; ++i)
      w[i] = (unsigned)f2b(tile[rr][kq + 2*i]) | ((unsigned)f2b(tile[rr][kq + 2*i + 1]) << 16);
    uint4* d = (uint4*)(dst + (size_t)(n0 + rr)*256 + k0 + kq);
    d[0] = *(uint4*)&w[0];
    d[1] = *(uint4*)&w[4];
  }
}

// ---------------- job tables for the mega kernel ----------------
struct MJobs {
  unsigned a[47], b[47], c[47];
  unsigned short tiles[47];      // 4 (M=64) or 16 (M=256)
  unsigned char start[10], cnt[10];
  unsigned short stTiles[10];    // total matmul tiles per stage
};

// ---------------- mega: prep + full chain + transposes + heads-bf16, one launch ----------------
__global__ __launch_bounds__(256) void mega_chain(
    const float* __restrict__ si, const float* __restrict__ cw,
    const float* __restrict__ em, const float* __restrict__ tm,
    const float* __restrict__ mask, float* __restrict__ ws, MJobs jb) {
  __shared__ float As[64][68];
  __shared__ float Bs[64][68];
  __shared__ float tile[64][65];
  __shared__ float rA[4], rB[4];
  unsigned* cnt = (unsigned*)(ws + OFF_CNT);
  int bid = blockIdx.x;

  // stage -1: prep softmax rows (1076 rows, grid-stride)
  for (int r = bid; r < 1076; r += GRID)
    prep_row(r, si, cw, em, tm, mask, ws, rA, rB);
  grid_sync(cnt, GRID);

  // stages 0..9: chain matmuls (+E^T in stage 0, +P^T in stage 5)
  for (int s = 0; s < 10; ++s) {
    int mt = jb.stTiles[s];
    int extra = (s == 0) ? 128 : (s == 5 ? 400 : 0);
    for (int j = bid; j < mt + extra; j += GRID) {
      if (j < mt) {
        int t = j, k = jb.start[s];
        while (t >= jb.tiles[k]) { t -= jb.tiles[k]; ++k; }
        int r0, n0;
        if (jb.tiles[k] == 16) { r0 = (t >> 2) << 6; n0 = (t & 3) << 6; }
        else { r0 = 0; n0 = t << 6; }
        gemm_tile(ws + jb.a[k], ws + jb.b[k], ws + jb.c[k], r0, n0, As, Bs);
      } else if (s == 0) {
        int e = j - mt;   // E^T: 32 n-tiles x 4 k-tiles
        trans_tile(ws + OFF_EPROB, NDIM, NDIM, (u16*)(ws + OFF_ET),
                   (e >> 2) * 64, (e & 3) * 64, tile);
      } else {
        int e = j - mt;   // P^T: 25 matrices x 16 tiles
        int m = e >> 4, t = e & 15;
        trans_tile(ws + OFF_POW + (size_t)m*MAT, SDIM, SDIM,
                   (u16*)(ws + OFF_PT) + (size_t)m*MAT,
                   (t >> 2) * 64, (t & 3) * 64, tile);
      }
    }
    grid_sync(cnt, GRID * (s + 2));
  }

  // final: heads f32 -> bf16 (20 jobs)
  int tid = threadIdx.x;
  for (int j = bid; j < 20; j += GRID) {
    const float* src = ws + OFF_HEADS + (size_t)j*HMAT;
    u16* dst = (u16*)(ws + OFF_HDB) + (size_t)j*HMAT;
    for (int i = tid; i < HMAT/2; i += 256) {
      float2 v = *(const float2*)(src + 2*i);
      ((unsigned*)dst)[i] = (unsigned)f2b(v.x) | ((unsigned)f2b(v.y) << 16);
    }
  }
}

// ---------------- MFMA helpers (64x256 out, K=256, chunked K=64, XOR-swizzled LDS) ----------------
__device__ __forceinline__ void stageAB(int tid, const u16* __restrict__ gA,
                                        const u16* __restrict__ gB, int kc,
                                        char* ldsA, char* ldsB) {
#pragma unroll
  for (int p = 0; p < 2; ++p) {
    int row = p*32 + (tid >> 3), slot = tid & 7;
    uint4 v = *(const uint4*)((const char*)gA + (size_t)row*512 + kc*128 + slot*16);
    *(uint4*)(ldsA + row*128 + ((slot*16) ^ ((row & 7) << 4))) = v;
  }
#pragma unroll
  for (int p = 0; p < 8; ++p) {
    int row = p*32 + (tid >> 3), slot = tid & 7;
    uint4 v = *(const uint4*)((const char*)gB + (size_t)row*512 + kc*128 + slot*16);
    *(uint4*)(ldsB + row*128 + ((slot*16) ^ ((row & 7) << 4))) = v;
  }
}

__device__ __forceinline__ void mfma_block(int g16, int c16, int wid,
                                           const char* ldsA, const char* ldsB,
                                           f32x4 (&acc)[4][4]) {
#pragma unroll
  for (int ks = 0; ks < 2; ++ks) {
    bf16x8 af[4], bfr[4];
    int kb = ks*64 + g16*16;
#pragma unroll
    for (int mf = 0; mf < 4; ++mf) {
      int row = mf*16 + c16;
      af[mf] = *(const bf16x8*)(ldsA + row*128 + (kb ^ ((row & 7) << 4)));
    }
#pragma unroll
    for (int nf = 0; nf < 4; ++nf) {
      int n = wid*64 + nf*16 + c16;
      bfr[nf] = *(const bf16x8*)(ldsB + n*128 + (kb ^ ((n & 7) << 4)));
    }
#pragma unroll
    for (int mf = 0; mf < 4; ++mf)
#pragma unroll
      for (int nf = 0; nf < 4; ++nf)
        acc[mf][nf] = __builtin_amdgcn_mfma_f32_16x16x32_bf16(af[mf], bfr[nf], acc[mf][nf], 0, 0, 0);
  }
}

// fill: h_t = H_b @ P_j (prob domain); writes log_hidden (f32, wave-contiguous NT) + hidden bf16
__global__ __launch_bounds__(256) void fill_mfma(float* __restrict__ ws_f, float* __restrict__ out) {
  int tt = blockIdx.x;
  int b = tt / 25, j = tt % 25;
  int tid = threadIdx.x;
  float* hid = out + OUT_HIDB + (size_t)tt*HMAT;
  u16* hb = (u16*)(ws_f + OFF_HB) + (size_t)tt*HMAT;
  if (j == 0) {
    const float* H = ws_f + OFF_HEADS + (size_t)b*HMAT;
    for (int i = tid; i < HMAT; i += 256) {
      float v = H[i];
      hid[i] = __logf(v);
      hb[i] = f2b(v);
    }
    return;
  }
  const u16* gA = (const u16*)(ws_f + OFF_HDB) + (size_t)b*HMAT;
  const u16* gB = (const u16*)(ws_f + OFF_PT) + (size_t)(j - 1)*MAT;
  __shared__ __align__(16) char smem[41600];
  char* ldsA = smem; char* ldsB = smem + 8192;
  int wid = tid >> 6, lane = tid & 63, g16 = lane >> 4, c16 = lane & 15;
  f32x4 acc[4][4];
#pragma unroll
  for (int mf = 0; mf < 4; ++mf)
#pragma unroll
    for (int nf = 0; nf < 4; ++nf) acc[mf][nf] = {0.f, 0.f, 0.f, 0.f};
  stageAB(tid, gA, gB, 0, ldsA, ldsB);
  __syncthreads();
  for (int kc = 0; kc < 4; ++kc) {
    mfma_block(g16, c16, wid, ldsA, ldsB, acc);
    __syncthreads();
    if (kc < 3) { stageAB(tid, gA, gB, kc + 1, ldsA, ldsB); __syncthreads(); }
  }
  // ---- restaged epilogue: wave-row-contiguous stores ----
  float* tile = (float*)smem;   // [32][TP]
#pragma unroll
  for (int p = 0; p < 2; ++p) {
    if (p) __syncthreads();
#pragma unroll
    for (int mf = 2*p; mf < 2*p + 2; ++mf)
#pragma unroll
      for (int r = 0; r < 4; ++r) {
        int lrow = mf*16 + g16*4 + r - 32*p;
#pragma unroll
        for (int nf = 0; nf < 4; ++nf) {
          int n = wid*64 + nf*16 + c16;
          tile[lrow*TP + n] = acc[mf][nf][r];
        }
      }
    __syncthreads();
#pragma unroll
    for (int r8 = 0; r8 < 8; ++r8) {
      int row = wid*8 + r8;
      int c = 32*p + row;
      f32x4 v = *(const f32x4*)&tile[row*TP + lane*4];
      f32x4 lg = {__logf(v[0]), __logf(v[1]), __logf(v[2]), __logf(v[3])};
      __builtin_nontemporal_store(lg, (f32x4*)(hid + (size_t)c*256 + lane*4));
      uint2 w;
      w.x = (unsigned)f2b(v[0]) | ((unsigned)f2b(v[1]) << 16);
      w.y = (unsigned)f2b(v[2]) | ((unsigned)f2b(v[3]) << 16);
      *(uint2*)(hb + (size_t)c*256 + lane*4) = w;
    }
  }
}

// emission: obs = hidden @ E (prob); wave-row-contiguous NT writes + fused log_obs reduction
__global__ __launch_bounds__(256) void emission_mfma(const float* __restrict__ ws_f, float* __restrict__ out) {
  int tt = blockIdx.y, n0 = blockIdx.x * 256;
  int tid = threadIdx.x;
  const u16* gA = (const u16*)(ws_f + OFF_HB) + (size_t)tt*HMAT;
  const u16* gB = (const u16*)(ws_f + OFF_ET) + (size_t)n0*256;
  __shared__ __align__(16) char smem[41600];
  __shared__ float sCw[64];
  char* ldsA = smem; char* ldsB = smem + 8192;
  if (tid < 64) sCw[tid] = ws_f[OFF_CW + tt*64 + tid];
  int wid = tid >> 6, lane = tid & 63, g16 = lane >> 4, c16 = lane & 15;
  f32x4 acc[4][4];
#pragma unroll
  for (int mf = 0; mf < 4; ++mf)
#pragma unroll
    for (int nf = 0; nf < 4; ++nf) acc[mf][nf] = {0.f, 0.f, 0.f, 0.f};
  stageAB(tid, gA, gB, 0, ldsA, ldsB);
  __syncthreads();
  for (int kc = 0; kc < 4; ++kc) {
    mfma_block(g16, c16, wid, ldsA, ldsB, acc);
    __syncthreads();
    if (kc < 3) { stageAB(tid, gA, gB, kc + 1, ldsA, ldsB); __syncthreads(); }
  }
  // fused log_obs reduction over c
  float s[4] = {0.f, 0.f, 0.f, 0.f};
  int nn[4];
#pragma unroll
  for (int nf = 0; nf < 4; ++nf) nn[nf] = n0 + wid*64 + nf*16 + c16;
#pragma unroll
  for (int mf = 0; mf < 4; ++mf)
#pragma unroll
    for (int r = 0; r < 4; ++r) {
      float wc = sCw[mf*16 + g16*4 + r];
#pragma unroll
      for (int nf = 0; nf < 4; ++nf) s[nf] += acc[mf][nf][r] * wc;
    }
#pragma unroll
  for (int nf = 0; nf < 4; ++nf) {
    s[nf] += __shfl_xor(s[nf], 16);
    s[nf] += __shfl_xor(s[nf], 32);
  }
  if (g16 == 0) {
#pragma unroll
    for (int nf = 0; nf < 4; ++nf)
      if (nn[nf] < NDIM) out[(size_t)tt*NDIM + nn[nf]] = __logf(s[nf]);
  }
  // restaged log_obs_ writes: wave-row-contiguous NT
  float* obsb = out + OUT_OBSB + (size_t)tt*CDIM*NDIM;
  float* tile = (float*)smem;   // [32][TP]
  bool okc = (n0 + (lane + 1)*4 <= NDIM);
#pragma unroll
  for (int p = 0; p < 2; ++p) {
    __syncthreads();
#pragma unroll
    for (int mf = 2*p; mf < 2*p + 2; ++mf)
#pragma unroll
      for (int r = 0; r < 4; ++r) {
        int lrow = mf*16 + g16*4 + r - 32*p;
#pragma unroll
        for (int nf = 0; nf < 4; ++nf) {
          int n = wid*64 + nf*16 + c16;
          tile[lrow*TP + n] = acc[mf][nf][r];
        }
      }
    __syncthreads();
#pragma unroll
    for (int r8 = 0; r8 < 8; ++r8) {
      int row = wid*8 + r8;
      int c = 32*p + row;
      if (okc) {
        f32x4 v = *(const f32x4*)&tile[row*TP + lane*4];
        f32x4 lg = {__logf(v[0]), __logf(v[1]), __logf(v[2]), __logf(v[3])};
        __builtin_nontemporal_store(lg, (f32x4*)(obsb + (size_t)c*NDIM + n0 + lane*4));
      }
    }
  }
}

extern "C" void kernel_launch(void* const* d_in, const int* in_sizes, int n_in,
                              void* d_out, int out_size, void* d_ws, size_t ws_size,
                              hipStream_t stream) {
  const float* si   = (const float*)d_in[0];
  const float* cw   = (const float*)d_in[1];
  const float* em   = (const float*)d_in[2];
  const float* tm   = (const float*)d_in[3];
  const float* mask = (const float*)d_in[4];
  float* out = (float*)d_out;
  float* ws  = (float*)d_ws;
  dim3 blk(256);

  // build chain job tables (mirrors the former 10-launch schedule)
  MJobs jb;
  int ji = 0;
  auto powOff  = [](int j){ return (unsigned)(OFF_POW + (unsigned)j*MAT); };
  auto headOff = [](int b){ return (unsigned)(OFF_HEADS + (unsigned)b*HMAT); };
  auto addJob = [&](unsigned a, unsigned b, unsigned c, int M) {
    jb.a[ji] = a; jb.b[ji] = b; jb.c[ji] = c; jb.tiles[ji] = (M == 256) ? 16 : 4; ++ji;
  };
  auto stage = [&](int s, int first) {
    jb.start[s] = (unsigned char)first; jb.cnt[s] = (unsigned char)(ji - first);
    int t = 0; for (int k = first; k < ji; ++k) t += jb.tiles[k];
    jb.stTiles[s] = (unsigned short)t;
  };
  int f;
  f = ji; addJob(powOff(0), powOff(0), powOff(1), 256); stage(0, f);
  f = ji; addJob(powOff(1), powOff(0), powOff(2), 256);
          addJob(powOff(1), powOff(1), powOff(3), 256); stage(1, f);
  f = ji; for (int i = 0; i < 4; ++i) addJob(powOff(3), powOff(i), powOff(4+i), 256); stage(2, f);
  f = ji; for (int i = 0; i < 8; ++i) addJob(powOff(7), powOff(i), powOff(8+i), 256); stage(3, f);
  f = ji; for (int i = 0; i < 9; ++i) addJob(powOff(15), powOff(i), powOff(16+i), 256); stage(4, f);
  f = ji; addJob(headOff(0), powOff(24), headOff(1), 64);
          addJob(powOff(24), powOff(24), OFF_R2, 256); stage(5, f);
  f = ji; addJob(headOff(0), OFF_R2, headOff(2), 64);
          addJob(headOff(1), OFF_R2, headOff(3), 64);
          addJob(OFF_R2, OFF_R2, OFF_R4, 256); stage(6, f);
  f = ji; for (int i = 0; i < 4; ++i) addJob(headOff(i), OFF_R4, headOff(4+i), 64);
          addJob(OFF_R4, OFF_R4, OFF_R8, 256); stage(7, f);
  f = ji; for (int i = 0; i < 8; ++i) addJob(headOff(i), OFF_R8, headOff(8+i), 64);
          addJob(OFF_R8, OFF_R8, OFF_R16, 256); stage(8, f);
  f = ji; for (int i = 0; i < 4; ++i) addJob(headOff(i), OFF_R16, headOff(16+i), 64); stage(9, f);

  // zero barrier counter (ws is re-poisoned to 0xAA before every call)
  hipMemsetAsync(ws + OFF_CNT, 0, sizeof(unsigned), stream);

  // one launch: prep + chain + transposes + heads-bf16
  mega_chain<<<dim3(GRID), blk, 0, stream>>>(si, cw, em, tm, mask, ws, jb);

  // all 500 h_t via MFMA -> log_hidden + hidden bf16
  fill_mfma<<<dim3(500), blk, 0, stream>>>(ws, out);

  // emission MFMA + fused log_obs reduction
  emission_mfma<<<dim3(8, 500), blk, 0, stream>>>(ws, out);
}

// Round 11
// 478.466 us; speedup vs baseline: 1.3708x; 1.3708x over previous
//
#include <hip/hip_runtime.h>
#include <cstddef>

typedef unsigned short u16;
typedef float f32x4 __attribute__((ext_vector_type(4)));
typedef short bf16x8 __attribute__((ext_vector_type(8)));

// Problem dims
#define SDIM 256
#define CDIM 64
#define NDIM 2000
#define TDIM 500

#define MAT  (SDIM*SDIM)   // 65536
#define HMAT (CDIM*SDIM)   // 16384

// ---- workspace layout (float offsets into d_ws) ----
// f32 regions:
#define OFF_POW    0u                        // [256][256] f32: P1 = softmax(Tm)
#define OFF_HEADS  (OFF_POW + MAT)           // [64][256] f32: h0
#define OFF_CW     (OFF_HEADS + HMAT)        // [500][64] f32 chain-weight probs
#define OFF_EPROB  (OFF_CW + 32000u)         // [256][2000] f32 emission probs
// u16 regions (float-offset base; u16 indexing inside):
#define OFF_ET     (OFF_EPROB + 512000u)     // E^T bf16 [2048 n][256 k]
#define OFF_PT     (OFF_ET + 262144u)        // P^T bf16 [25][256 n][256 k]
#define OFF_PPB    (OFF_PT + 819200u)        // P plain bf16 [25][256 m][256 k]
#define OFF_RPB    (OFF_PPB + 819200u)       // R plain bf16 [4][256][256]  (R2,R4,R8,R16)
#define OFF_RPT    (OFF_RPB + 131072u)       // R^T bf16 [4][256][256]
#define OFF_HDB    (OFF_RPT + 131072u)       // heads plain bf16 [20][64][256]
#define OFF_HB     (OFF_HDB + 163840u)       // hidden bf16 [500][64][256]
// end ~ 7.05M floats ~ 28 MB

// u16 index helper (float offset -> u16 offset)
#define U16OFF(X) ((unsigned)((X) * 2u))

// d_out layout: log_obs [500][2000] | log_obs_ [500][64][2000] | log_hidden [500][64][256]
#define OUT_OBSB  1000000u
#define OUT_HIDB  65000000u

#define TP 260   // padded LDS tile stride (floats)

__device__ __forceinline__ float waveMax(float v) {
#pragma unroll
  for (int o = 32; o >= 1; o >>= 1) v = fmaxf(v, __shfl_xor(v, o));
  return v;
}
__device__ __forceinline__ float waveSum(float v) {
#pragma unroll
  for (int o = 32; o >= 1; o >>= 1) v += __shfl_xor(v, o);
  return v;
}
__device__ __forceinline__ u16 f2b(float f) {
  union { float f; unsigned u; } x; x.f = f;
  return (u16)((x.u + 0x7fffu + ((x.u >> 16) & 1u)) >> 16);
}
__device__ __forceinline__ float b2f(u16 b) {
  union { unsigned u; float f; } x; x.u = ((unsigned)b) << 16;
  return x.f;
}

// ---------------- prep: row softmax -> PROBABILITIES for all four inputs ----------------
__global__ __launch_bounds__(256) void prep_prob(
    const float* __restrict__ si, const float* __restrict__ cw,
    const float* __restrict__ em, const float* __restrict__ tm,
    const float* __restrict__ mask, float* __restrict__ ws) {
  int b = blockIdx.x;
  const float* src; const float* msk = nullptr; float* dst; int len;
  if (b < 64)       { src = si + b*SDIM;                 dst = ws + OFF_HEADS + b*SDIM; len = SDIM; }
  else if (b < 564) { int r = b - 64;  src = cw + r*64;  dst = ws + OFF_CW + r*64;      len = 64;   }
  else if (b < 820) { int r = b - 564; src = tm + (size_t)r*SDIM; dst = ws + OFF_POW + (size_t)r*SDIM; len = SDIM; }
  else              { int r = b - 820; src = em + (size_t)r*NDIM; dst = ws + OFF_EPROB + (size_t)r*NDIM; len = NDIM; msk = mask + (size_t)r*NDIM; }
  int tid = threadIdx.x;
  __shared__ float rA[4], rB[4];
  float m = -INFINITY;
  for (int i = tid; i < len; i += 256) {
    float v = src[i];
    if (msk) v += __logf(msk[i]);
    m = fmaxf(m, v);
  }
  m = waveMax(m);
  if ((tid & 63) == 0) rA[tid >> 6] = m;
  __syncthreads();
  m = fmaxf(fmaxf(rA[0], rA[1]), fmaxf(rA[2], rA[3]));
  float s = 0.f;
  for (int i = tid; i < len; i += 256) {
    float v = src[i];
    if (msk) v += __logf(msk[i]);
    s += __expf(v - m);
  }
  s = waveSum(s);
  if ((tid & 63) == 0) rB[tid >> 6] = s;
  __syncthreads();
  s = rB[0] + rB[1] + rB[2] + rB[3];
  float inv = 1.f / s;
  for (int i = tid; i < len; i += 256) {
    float v = src[i];
    if (msk) v += __logf(msk[i]);
    dst[i] = __expf(v - m) * inv;
  }
}

// ---------------- 64x64 transpose tile fp32 -> bf16 [n][256] ----------------
__device__ void trans_tile(const float* __restrict__ src, int ldn, int nReal,
                           u16* __restrict__ dst, int n0, int k0,
                           float (*tile)[65]) {
  int tid = threadIdx.x;
  {
    int kk = tid >> 2, p = tid & 3;
    const float* s = src + (size_t)(k0 + kk)*ldn + n0 + p*16;
#pragma unroll
    for (int i = 0; i < 16; ++i) {
      int n = n0 + p*16 + i;
      tile[p*16 + i][kk] = (n < nReal) ? s[i] : 0.f;
    }
  }
  __syncthreads();
  {
    int rr = tid >> 2, kq = (tid & 3) * 16;
    unsigned w[8];
#pragma unroll
    for (int i = 0; i < 8; ++i)
      w[i] = (unsigned)f2b(tile[rr][kq + 2*i]) | ((unsigned)f2b(tile[rr][kq + 2*i + 1]) << 16);
    uint4* d = (uint4*)(dst + (size_t)(n0 + rr)*256 + k0 + kq);
    d[0] = *(uint4*)&w[0];
    d[1] = *(uint4*)&w[4];
  }
}

// ---------------- prep2: E^T (128 tiles) + P1^T (16) + P1 plain cast (8) + h0 cast (2) ----------------
__global__ __launch_bounds__(256) void prep2(float* __restrict__ ws) {
  __shared__ float tile[64][65];
  int b = blockIdx.x, tid = threadIdx.x;
  if (b < 128) {
    trans_tile(ws + OFF_EPROB, NDIM, NDIM, (u16*)ws + U16OFF(OFF_ET), (b >> 2)*64, (b & 3)*64, tile);
  } else if (b < 144) {
    int t = b - 128;
    trans_tile(ws + OFF_POW, SDIM, SDIM, (u16*)ws + U16OFF(OFF_PT), (t >> 2)*64, (t & 3)*64, tile);
  } else if (b < 152) {
    int t = b - 144;
    const float* s = ws + OFF_POW + t*8192;
    unsigned* d = (unsigned*)((u16*)ws + U16OFF(OFF_PPB)) + t*4096;
    for (int i = tid; i < 4096; i += 256) {
      float2 v = *(const float2*)(s + 2*i);
      d[i] = (unsigned)f2b(v.x) | ((unsigned)f2b(v.y) << 16);
    }
  } else {
    int t = b - 152;
    const float* s = ws + OFF_HEADS + t*8192;
    unsigned* d = (unsigned*)((u16*)ws + U16OFF(OFF_HDB)) + t*4096;
    for (int i = tid; i < 4096; i += 256) {
      float2 v = *(const float2*)(s + 2*i);
      d[i] = (unsigned)f2b(v.x) | ((unsigned)f2b(v.y) << 16);
    }
  }
}

// ---------------- MFMA helpers (64x256 out, K=256, chunked K=64, XOR-swizzled LDS) ----------------
__device__ __forceinline__ void stageAB(int tid, const u16* __restrict__ gA,
                                        const u16* __restrict__ gB, int kc,
                                        char* ldsA, char* ldsB) {
#pragma unroll
  for (int p = 0; p < 2; ++p) {
    int row = p*32 + (tid >> 3), slot = tid & 7;
    uint4 v = *(const uint4*)((const char*)gA + (size_t)row*512 + kc*128 + slot*16);
    *(uint4*)(ldsA + row*128 + ((slot*16) ^ ((row & 7) << 4))) = v;
  }
#pragma unroll
  for (int p = 0; p < 8; ++p) {
    int row = p*32 + (tid >> 3), slot = tid & 7;
    uint4 v = *(const uint4*)((const char*)gB + (size_t)row*512 + kc*128 + slot*16);
    *(uint4*)(ldsB + row*128 + ((slot*16) ^ ((row & 7) << 4))) = v;
  }
}

__device__ __forceinline__ void mfma_block(int g16, int c16, int wid,
                                           const char* ldsA, const char* ldsB,
                                           f32x4 (&acc)[4][4]) {
#pragma unroll
  for (int ks = 0; ks < 2; ++ks) {
    bf16x8 af[4], bfr[4];
    int kb = ks*64 + g16*16;
#pragma unroll
    for (int mf = 0; mf < 4; ++mf) {
      int row = mf*16 + c16;
      af[mf] = *(const bf16x8*)(ldsA + row*128 + (kb ^ ((row & 7) << 4)));
    }
#pragma unroll
    for (int nf = 0; nf < 4; ++nf) {
      int n = wid*64 + nf*16 + c16;
      bfr[nf] = *(const bf16x8*)(ldsB + n*128 + (kb ^ ((n & 7) << 4)));
    }
#pragma unroll
    for (int mf = 0; mf < 4; ++mf)
#pragma unroll
      for (int nf = 0; nf < 4; ++nf)
        acc[mf][nf] = __builtin_amdgcn_mfma_f32_16x16x32_bf16(af[mf], bfr[nf], acc[mf][nf], 0, 0, 0);
  }
}

// ---------------- chain: C = A @ B in bf16 MFMA, dual-form epilogue ----------------
struct CJobs {
  int n;
  unsigned a[12], b[12], cp[12], ct[12];   // u16 offsets; ct==0xFFFFFFFF -> skip transposed
  unsigned short tiles[12];                // 4 (M=256) or 1 (M=64)
};

__global__ __launch_bounds__(256) void chain_mfma(float* __restrict__ ws, CJobs jb) {
  int t = blockIdx.x, k = 0;
  while (t >= jb.tiles[k]) { t -= jb.tiles[k]; ++k; }
  int r0 = t * 64;
  u16* wsu = (u16*)ws;
  const u16* gA = wsu + jb.a[k] + (size_t)r0*256;
  const u16* gB = wsu + jb.b[k];
  u16* cp = wsu + jb.cp[k] + (size_t)r0*256;
  bool hasCT = (jb.ct[k] != 0xFFFFFFFFu);
  u16* ctB = wsu + (hasCT ? jb.ct[k] : 0u);
  int tid = threadIdx.x;
  __shared__ __align__(16) char smem[41600];
  char* ldsA = smem; char* ldsB = smem + 8192;
  int wid = tid >> 6, lane = tid & 63, g16 = lane >> 4, c16 = lane & 15;
  f32x4 acc[4][4];
#pragma unroll
  for (int mf = 0; mf < 4; ++mf)
#pragma unroll
    for (int nf = 0; nf < 4; ++nf) acc[mf][nf] = {0.f, 0.f, 0.f, 0.f};
  stageAB(tid, gA, gB, 0, ldsA, ldsB);
  __syncthreads();
  for (int kc = 0; kc < 4; ++kc) {
    mfma_block(g16, c16, wid, ldsA, ldsB, acc);
    __syncthreads();
    if (kc < 3) { stageAB(tid, gA, gB, kc + 1, ldsA, ldsB); __syncthreads(); }
  }
  // dual-form epilogue: two 32-row passes through LDS
  float* tile = (float*)smem;   // [32][TP]
#pragma unroll
  for (int p = 0; p < 2; ++p) {
    if (p) __syncthreads();
#pragma unroll
    for (int mf = 2*p; mf < 2*p + 2; ++mf)
#pragma unroll
      for (int r = 0; r < 4; ++r) {
        int lrow = mf*16 + g16*4 + r - 32*p;
#pragma unroll
        for (int nf = 0; nf < 4; ++nf) {
          int n = wid*64 + nf*16 + c16;
          tile[lrow*TP + n] = acc[mf][nf][r];
        }
      }
    __syncthreads();
    // plain rows: wave w -> rows w*8..w*8+7; lanes cover one 512 B bf16 row
#pragma unroll
    for (int r8 = 0; r8 < 8; ++r8) {
      int row = wid*8 + r8;
      int m = 32*p + row;
      f32x4 v = *(const f32x4*)&tile[row*TP + lane*4];
      uint2 w;
      w.x = (unsigned)f2b(v[0]) | ((unsigned)f2b(v[1]) << 16);
      w.y = (unsigned)f2b(v[2]) | ((unsigned)f2b(v[3]) << 16);
      *(uint2*)(cp + (size_t)m*256 + lane*4) = w;
    }
    // transposed: lane owns column n; writes 64 B sector CT[n][r0+32p .. +31]
    if (hasCT) {
#pragma unroll
      for (int it = 0; it < 4; ++it) {
        int n = it*64 + lane;
        unsigned w[16];
#pragma unroll
        for (int j = 0; j < 16; ++j)
          w[j] = (unsigned)f2b(tile[2*j*TP + n]) | ((unsigned)f2b(tile[(2*j+1)*TP + n]) << 16);
        uint4* d = (uint4*)(ctB + (size_t)n*256 + r0 + 32*p);
        d[0] = *(uint4*)&w[0];
        d[1] = *(uint4*)&w[4];
        d[2] = *(uint4*)&w[8];
        d[3] = *(uint4*)&w[12];
      }
    }
  }
}

// fill: h_t = H_b @ P_j (prob domain); writes log_hidden (f32, wave-contiguous NT) + hidden bf16
__global__ __launch_bounds__(256) void fill_mfma(float* __restrict__ ws_f, float* __restrict__ out) {
  int tt = blockIdx.x;
  int b = tt / 25, j = tt % 25;
  int tid = threadIdx.x;
  float* hid = out + OUT_HIDB + (size_t)tt*HMAT;
  u16* hb = (u16*)ws_f + U16OFF(OFF_HB) + (size_t)tt*HMAT;
  const u16* gA = (u16*)ws_f + U16OFF(OFF_HDB) + (size_t)b*HMAT;
  if (j == 0) {
    for (int i = tid; i < HMAT; i += 256) {
      u16 hv = gA[i];
      hid[i] = __logf(b2f(hv));
      hb[i] = hv;
    }
    return;
  }
  const u16* gB = (u16*)ws_f + U16OFF(OFF_PT) + (size_t)(j - 1)*MAT;
  __shared__ __align__(16) char smem[41600];
  char* ldsA = smem; char* ldsB = smem + 8192;
  int wid = tid >> 6, lane = tid & 63, g16 = lane >> 4, c16 = lane & 15;
  f32x4 acc[4][4];
#pragma unroll
  for (int mf = 0; mf < 4; ++mf)
#pragma unroll
    for (int nf = 0; nf < 4; ++nf) acc[mf][nf] = {0.f, 0.f, 0.f, 0.f};
  stageAB(tid, gA, gB, 0, ldsA, ldsB);
  __syncthreads();
  for (int kc = 0; kc < 4; ++kc) {
    mfma_block(g16, c16, wid, ldsA, ldsB, acc);
    __syncthreads();
    if (kc < 3) { stageAB(tid, gA, gB, kc + 1, ldsA, ldsB); __syncthreads(); }
  }
  float* tile = (float*)smem;   // [32][TP]
#pragma unroll
  for (int p = 0; p < 2; ++p) {
    if (p) __syncthreads();
#pragma unroll
    for (int mf = 2*p; mf < 2*p + 2; ++mf)
#pragma unroll
      for (int r = 0; r < 4; ++r) {
        int lrow = mf*16 + g16*4 + r - 32*p;
#pragma unroll
        for (int nf = 0; nf < 4; ++nf) {
          int n = wid*64 + nf*16 + c16;
          tile[lrow*TP + n] = acc[mf][nf][r];
        }
      }
    __syncthreads();
#pragma unroll
    for (int r8 = 0; r8 < 8; ++r8) {
      int row = wid*8 + r8;
      int c = 32*p + row;
      f32x4 v = *(const f32x4*)&tile[row*TP + lane*4];
      f32x4 lg = {__logf(v[0]), __logf(v[1]), __logf(v[2]), __logf(v[3])};
      __builtin_nontemporal_store(lg, (f32x4*)(hid + (size_t)c*256 + lane*4));
      uint2 w;
      w.x = (unsigned)f2b(v[0]) | ((unsigned)f2b(v[1]) << 16);
      w.y = (unsigned)f2b(v[2]) | ((unsigned)f2b(v[3]) << 16);
      *(uint2*)(hb + (size_t)c*256 + lane*4) = w;
    }
  }
}

// emission: obs = hidden @ E (prob); wave-row-contiguous NT writes + fused log_obs reduction
__global__ __launch_bounds__(256) void emission_mfma(const float* __restrict__ ws_f, float* __restrict__ out) {
  int tt = blockIdx.y, n0 = blockIdx.x * 256;
  int tid = threadIdx.x;
  const u16* gA = (const u16*)ws_f + U16OFF(OFF_HB) + (size_t)tt*HMAT;
  const u16* gB = (const u16*)ws_f + U16OFF(OFF_ET) + (size_t)n0*256;
  __shared__ __align__(16) char smem[41600];
  __shared__ float sCw[64];
  char* ldsA = smem; char* ldsB = smem + 8192;
  if (tid < 64) sCw[tid] = ws_f[OFF_CW + tt*64 + tid];
  int wid = tid >> 6, lane = tid & 63, g16 = lane >> 4, c16 = lane & 15;
  f32x4 acc[4][4];
#pragma unroll
  for (int mf = 0; mf < 4; ++mf)
#pragma unroll
    for (int nf = 0; nf < 4; ++nf) acc[mf][nf] = {0.f, 0.f, 0.f, 0.f};
  stageAB(tid, gA, gB, 0, ldsA, ldsB);
  __syncthreads();
  for (int kc = 0; kc < 4; ++kc) {
    mfma_block(g16, c16, wid, ldsA, ldsB, acc);
    __syncthreads();
    if (kc < 3) { stageAB(tid, gA, gB, kc + 1, ldsA, ldsB); __syncthreads(); }
  }
  // fused log_obs reduction over c
  float s[4] = {0.f, 0.f, 0.f, 0.f};
  int nn[4];
#pragma unroll
  for (int nf = 0; nf < 4; ++nf) nn[nf] = n0 + wid*64 + nf*16 + c16;
#pragma unroll
  for (int mf = 0; mf < 4; ++mf)
#pragma unroll
    for (int r = 0; r < 4; ++r) {
      float wc = sCw[mf*16 + g16*4 + r];
#pragma unroll
      for (int nf = 0; nf < 4; ++nf) s[nf] += acc[mf][nf][r] * wc;
    }
#pragma unroll
  for (int nf = 0; nf < 4; ++nf) {
    s[nf] += __shfl_xor(s[nf], 16);
    s[nf] += __shfl_xor(s[nf], 32);
  }
  if (g16 == 0) {
#pragma unroll
    for (int nf = 0; nf < 4; ++nf)
      if (nn[nf] < NDIM) out[(size_t)tt*NDIM + nn[nf]] = __logf(s[nf]);
  }
  // restaged log_obs_ writes: wave-row-contiguous NT
  float* obsb = out + OUT_OBSB + (size_t)tt*CDIM*NDIM;
  float* tile = (float*)smem;   // [32][TP]
  bool okc = (n0 + (lane + 1)*4 <= NDIM);
#pragma unroll
  for (int p = 0; p < 2; ++p) {
    __syncthreads();
#pragma unroll
    for (int mf = 2*p; mf < 2*p + 2; ++mf)
#pragma unroll
      for (int r = 0; r < 4; ++r) {
        int lrow = mf*16 + g16*4 + r - 32*p;
#pragma unroll
        for (int nf = 0; nf < 4; ++nf) {
          int n = wid*64 + nf*16 + c16;
          tile[lrow*TP + n] = acc[mf][nf][r];
        }
      }
    __syncthreads();
#pragma unroll
    for (int r8 = 0; r8 < 8; ++r8) {
      int row = wid*8 + r8;
      int c = 32*p + row;
      if (okc) {
        f32x4 v = *(const f32x4*)&tile[row*TP + lane*4];
        f32x4 lg = {__logf(v[0]), __logf(v[1]), __logf(v[2]), __logf(v[3])};
        __builtin_nontemporal_store(lg, (f32x4*)(obsb + (size_t)c*NDIM + n0 + lane*4));
      }
    }
  }
}

extern "C" void kernel_launch(void* const* d_in, const int* in_sizes, int n_in,
                              void* d_out, int out_size, void* d_ws, size_t ws_size,
                              hipStream_t stream) {
  const float* si   = (const float*)d_in[0];
  const float* cw   = (const float*)d_in[1];
  const float* em   = (const float*)d_in[2];
  const float* tm   = (const float*)d_in[3];
  const float* mask = (const float*)d_in[4];
  float* out = (float*)d_out;
  float* ws  = (float*)d_ws;
  dim3 blk(256);

  prep_prob<<<dim3(1076), blk, 0, stream>>>(si, cw, em, tm, mask, ws);
  prep2<<<dim3(154), blk, 0, stream>>>(ws);

  // u16-offset helpers
  auto ppb = [](int i){ return U16OFF(OFF_PPB) + (unsigned)i*MAT; };
  auto pt  = [](int i){ return U16OFF(OFF_PT)  + (unsigned)i*MAT; };
  auto rpb = [](int i){ return U16OFF(OFF_RPB) + (unsigned)i*MAT; };
  auto rpt = [](int i){ return U16OFF(OFF_RPT) + (unsigned)i*MAT; };
  auto hdb = [](int b){ return U16OFF(OFF_HDB) + (unsigned)b*HMAT; };

  CJobs jb;
  int ji = 0, total = 0;
  auto add = [&](unsigned a, unsigned b, unsigned cp, unsigned ct, int M) {
    jb.a[ji] = a; jb.b[ji] = b; jb.cp[ji] = cp; jb.ct[ji] = ct;
    jb.tiles[ji] = (M == 256) ? 4 : 1; total += jb.tiles[ji]; ++ji;
  };
  auto launch = [&]() {
    jb.n = ji;
    chain_mfma<<<dim3(total), blk, 0, stream>>>(ws, jb);
    ji = 0; total = 0;
  };
  const unsigned NOCT = 0xFFFFFFFFu;

  // powers P_1..P_25 by doubling (pow[i] = Tm^(i+1); P1 forms from prep2)
  add(ppb(0), pt(0), ppb(1), pt(1), 256); launch();
  add(ppb(1), pt(0), ppb(2), pt(2), 256);
  add(ppb(1), pt(1), ppb(3), pt(3), 256); launch();
  for (int i = 0; i < 4; ++i) add(ppb(3), pt(i), ppb(4+i), pt(4+i), 256); launch();
  for (int i = 0; i < 8; ++i) add(ppb(7), pt(i), ppb(8+i), pt(8+i), 256); launch();
  for (int i = 0; i < 9; ++i) add(ppb(15), pt(i), ppb(16+i), pt(16+i), 256); launch();

  // heads + R doubling
  add(hdb(0), pt(24), hdb(1), NOCT, 64);
  add(ppb(24), pt(24), rpb(0), rpt(0), 256); launch();
  add(hdb(0), rpt(0), hdb(2), NOCT, 64);
  add(hdb(1), rpt(0), hdb(3), NOCT, 64);
  add(rpb(0), rpt(0), rpb(1), rpt(1), 256); launch();
  for (int i = 0; i < 4; ++i) add(hdb(i), rpt(1), hdb(4+i), NOCT, 64);
  add(rpb(1), rpt(1), rpb(2), rpt(2), 256); launch();
  for (int i = 0; i < 8; ++i) add(hdb(i), rpt(2), hdb(8+i), NOCT, 64);
  add(rpb(2), rpt(2), rpb(3), rpt(3), 256); launch();
  for (int i = 0; i < 4; ++i) add(hdb(i), rpt(3), hdb(16+i), NOCT, 64); launch();

  // all 500 h_t via MFMA -> log_hidden + hidden bf16
  fill_mfma<<<dim3(500), blk, 0, stream>>>(ws, out);

  // emission MFMA + fused log_obs reduction
  emission_mfma<<<dim3(8, 500), blk, 0, stream>>>(ws, out);
}